// Round 5
// baseline (742.867 us; speedup 1.0000x reference)
//
#include <hip/hip_runtime.h>
#include <hip/hip_bf16.h>

// CensorNet T=512,B=256,I=128,H=256 GRU scan + BCE decode.
// R9: single fused kernel. The x@Wih GEMM moves INSIDE rec as a per-16-step
// chunk phase: M=16 bf16 MFMA tiles are fully packed (4 time steps x 4 batch
// rows -- zero M padding), gi is written straight to a 98KB LDS buffer and
// the scan reads it via ds_read (no gi HBM round-trip, no xconv/gemm1
// kernels, no h_ws persistence; 2 launches total). GEMM fragment K-order and
// epilogue expressions are copied verbatim from gemm1 -> bit-identical gi;
// scan body identical to R8 -> absmax 0.0 expected.
// LDS: gi 98304 + x 17408 + Wih-slab 34816 + hb 2304 + lp 1024 = 153856 B
// (1 block/CU, 64 blocks).

typedef __bf16 bf16x8_t __attribute__((ext_vector_type(8)));
typedef float floatx4_t __attribute__((ext_vector_type(4)));
typedef int intx4_t __attribute__((ext_vector_type(4)));
typedef unsigned int u32;
typedef u32 u32x4_t __attribute__((ext_vector_type(4)));

#define SW 2032.0f
#define SH 127.0f
#define INV_S (1.0f / (127.0f * 2032.0f))
#define NL2E (-1.44269504088896f) /* -log2(e) */
#define CRZ (NL2E * INV_S)
#define CN (2.0f * NL2E * INV_S)
#define CH 16

static __device__ inline u32 pack2bf(float a, float b) {
  __bf16 x = (__bf16)a, y = (__bf16)b;
  unsigned short ux = *(unsigned short*)&x, uy = *(unsigned short*)&y;
  return (u32)ux | ((u32)uy << 16);
}

// ---------------- prep: quantize W_hh/W_dec to i8, Wih->bf16 --------------
__global__ void prep_kernel(const float* __restrict__ Whh,
                            const float* __restrict__ Wdec,
                            const float* __restrict__ Wih,
                            char* __restrict__ Wq, char* __restrict__ wdq,
                            __bf16* __restrict__ Wihb,
                            float* __restrict__ out) {
  int idx = blockIdx.x * 256 + threadIdx.x;  // 65536 total
  for (int i = idx; i < 768 * 256; i += 65536) {
    int v = (int)rintf(Whh[i] * SW);
    v = v > 127 ? 127 : (v < -127 ? -127 : v);
    Wq[i] = (char)v;
  }
  for (int i = idx; i < 768 * 128; i += 65536) Wihb[i] = (__bf16)Wih[i];
  if (idx < 256) {
    int v = (int)rintf(Wdec[idx] * SW);
    v = v > 127 ? 127 : (v < -127 ? -127 : v);
    wdq[idx] = (char)v;
  }
  if (idx == 0) out[0] = 0.f;
}

// ---------------- rec2: fused gi-GEMM + serial scan -----------------------
__global__ __launch_bounds__(1024) void rec2_kernel(
    const char* __restrict__ Wq,      // [768][256] i8
    const char* __restrict__ wdq,     // [256] i8
    const float* __restrict__ x,      // [512][256][128] fp32
    const float* __restrict__ gt,     // [512][256]
    const float* __restrict__ bdec, const float* __restrict__ bhh,
    const float* __restrict__ bih,
    const __bf16* __restrict__ Wihb,  // [768][128] bf16
    float* __restrict__ out) {
  __shared__ u32 gi_s[CH][3][512];    // 98304 B: [tloc][gate][boff]
  __shared__ __bf16 xs[64][136];      // 17408 B: rows = tloc*4 + batchrow
  __shared__ __bf16 wsb[128][136];    // 34816 B: Wih slab (128 n-rows)
  __shared__ char hb[2][4][288];      // 2304 B:  h i8 ping-pong
  __shared__ float lp[4][64];         // 1024 B:  decoder partials (exact ints)

  const int tid = threadIdx.x;
  const int w = tid >> 6, lane = tid & 63;  // wave 0..15
  const int q = lane >> 4, nh = lane & 15;  // q = batch row 0..3
  const int g = blockIdx.x;                 // batch slice 0..63 (4 rows)
  const int col = w * 16 + nh;              // scan: lane's h col
  const int wp = w >> 1;                    // gi dword group
  const int hi = w & 1;                     // lo/hi bf16 half (wave-uniform)
  const int boff = wp * 64 + q * 16 + nh;

  // W_hh fragments (i8, B-operand): wave owns cols w*16..+15 for 3 gates
  intx4_t wf[3][4];
#pragma unroll
  for (int c = 0; c < 3; ++c) {
    const int n = c * 256 + col;
#pragma unroll
    for (int kb = 0; kb < 4; ++kb)
      wf[c][kb] = *(const intx4_t*)(Wq + (size_t)n * 256 + kb * 64 + q * 16);
  }
  // Wdec fragment: wave 12+kb owns k-block kb (one per SIMD)
  intx4_t wdfk;
  {
    const int kb = (w >= 12) ? (w - 12) : 0;
    intx4_t z = {0, 0, 0, 0};
    intx4_t v = *(const intx4_t*)(wdq + kb * 64 + q * 16);
    wdfk = (nh == 0) ? v : z;  // B col 0 = Wdec
  }

  const float bn2 = 2.0f * NL2E * bhh[512 + col];
  const float bdec0 = bdec[0];

  // zero hb (h0 = 0; reference h0 is zeros)
  for (int i2 = tid; i2 < 576; i2 += 1024) ((u32*)hb)[i2] = 0;
  float ho = 0.f;
  float loss = 0.f;

  // GEMM-phase wave tiling: pair of n-tiles (cols 16 apart) x one b-tile
  const int wpair = w & 3;   // n-pair within slab: cols wpair*32 .. +31
  const int btile = w >> 2;  // b-tile: LDS x rows btile*16 .. +15

#pragma unroll 1
  for (int c = 0; c < 32; ++c) {
    const int t0c = c * CH;

    // ---- stage x chunk: fp32 -> bf16, 64 rows x 128 ----
    {
      const int row = tid >> 4, cc = (tid & 15) * 8;
      const size_t gx =
          ((size_t)(t0c + (row >> 2)) * 256 + g * 4 + (row & 3)) * 128 + cc;
      floatx4_t a = *(const floatx4_t*)(x + gx);
      floatx4_t b = *(const floatx4_t*)(x + gx + 4);
      bf16x8_t tv;
#pragma unroll
      for (int j = 0; j < 4; ++j) {
        tv[j] = (__bf16)a[j];
        tv[4 + j] = (__bf16)b[j];
      }
      *(bf16x8_t*)&xs[row][cc] = tv;
    }

    // ---- 6 Wih slabs: gi = scale*(x @ Wih^T + biases) -> gi_s ----
#pragma unroll 1
    for (int s = 0; s < 6; ++s) {
      __syncthreads();  // prev slab MFMA done with wsb (s=0: xs/hb staged)
      {
        const int row = tid >> 3, cc = (tid & 7) * 16;
        const __bf16* src = Wihb + (size_t)(s * 128 + row) * 128 + cc;
        *(bf16x8_t*)&wsb[row][cc] = *(const bf16x8_t*)src;
        *(bf16x8_t*)&wsb[row][cc + 8] = *(const bf16x8_t*)(src + 8);
      }
      __syncthreads();

      floatx4_t a0, a1;
#pragma unroll
      for (int j = 0; j < 4; ++j) {
        a0[j] = 0.f;
        a1[j] = 0.f;
      }
#pragma unroll
      for (int kk = 0; kk < 4; ++kk) {
        bf16x8_t A0 = *(const bf16x8_t*)&wsb[wpair * 32 + nh][kk * 32 + q * 8];
        bf16x8_t A1 =
            *(const bf16x8_t*)&wsb[wpair * 32 + 16 + nh][kk * 32 + q * 8];
        bf16x8_t B = *(const bf16x8_t*)&xs[btile * 16 + nh][kk * 32 + q * 8];
        a0 = __builtin_amdgcn_mfma_f32_16x16x32_bf16(A0, B, a0, 0, 0, 0);
        a1 = __builtin_amdgcn_mfma_f32_16x16x32_bf16(A1, B, a1, 0, 0, 0);
      }

      const int gate = s >> 1;
      const float sc = (gate < 2) ? NL2E : (2.0f * NL2E);
      const int n0 = s * 128 + wpair * 32 + q * 4;
      floatx4_t biasA = *(const floatx4_t*)(bih + n0);
      floatx4_t biasB = *(const floatx4_t*)(bih + n0 + 16);
      if (gate < 2) {
        floatx4_t c1 = *(const floatx4_t*)(bhh + n0);
        floatx4_t c2 = *(const floatx4_t*)(bhh + n0 + 16);
#pragma unroll
        for (int j = 0; j < 4; ++j) {
          biasA[j] += c1[j];
          biasB[j] += c2[j];
        }
      }
      const int wrec = (s & 1) * 4 + wpair;
      const int b = btile * 16 + nh, tl2 = b >> 2, jb = b & 3;
      u32x4_t pv;
#pragma unroll
      for (int j = 0; j < 4; ++j)
        pv[j] = pack2bf((a0[j] + biasA[j]) * sc, (a1[j] + biasB[j]) * sc);
      *(u32x4_t*)&gi_s[tl2][gate][wrec * 64 + jb * 16 + q * 4] = pv;
    }
    __syncthreads();  // gi_s complete & visible

    // ---- scan CH steps (15 in last chunk) ----
    const int te = (c == 31) ? 15 : 16;
#pragma unroll 1
    for (int tl = 0; tl < te; ++tl) {
      const int t = t0c + tl;
      const int pb = t & 1;
      intx4_t hbf[4];  // A-operand: row m holds h[m>>2] (4-lane broadcast)
#pragma unroll
      for (int kb = 0; kb < 4; ++kb)
        hbf[kb] = *(const intx4_t*)&hb[pb][nh >> 2][kb * 64 + q * 16];

      const u32 G0 = gi_s[tl][0][boff];
      const u32 G1 = gi_s[tl][1][boff];
      const u32 G2 = gi_s[tl][2][boff];
      float gv0, gv1, gv2;
      if (hi) {
        gv0 = __uint_as_float(G0 & 0xffff0000u);
        gv1 = __uint_as_float(G1 & 0xffff0000u);
        gv2 = __uint_as_float(G2 & 0xffff0000u);
      } else {
        gv0 = __uint_as_float(G0 << 16);
        gv1 = __uint_as_float(G1 << 16);
        gv2 = __uint_as_float(G2 << 16);
      }

      intx4_t acc[3];
#pragma unroll
      for (int cs = 0; cs < 3; ++cs)
#pragma unroll
        for (int jj = 0; jj < 4; ++jj) acc[cs][jj] = 0;

#pragma unroll
      for (int kb = 0; kb < 4; ++kb)
#pragma unroll
        for (int cs = 0; cs < 3; ++cs)
          acc[cs] = __builtin_amdgcn_mfma_i32_16x16x64_i8(hbf[kb], wf[cs][kb],
                                                          acc[cs], 0, 0, 0);
      // acc[cs][0] = gh[batch q][col] for gate cs -- in-register.

      // decoder partial: waves 12..15, one k-block each (one per SIMD)
      if (w >= 12) {
        intx4_t hsel = (w == 12)   ? hbf[0]
                       : (w == 13) ? hbf[1]
                       : (w == 14) ? hbf[2]
                                   : hbf[3];
        intx4_t facc = {0, 0, 0, 0};
        facc =
            __builtin_amdgcn_mfma_i32_16x16x64_i8(hsel, wdfk, facc, 0, 0, 0);
        if (nh == 0 && t >= 1) lp[w - 12][tl * 4 + q] = (float)facc[0];
      }

      float rr0 = __builtin_amdgcn_rcpf(
          1.f + __builtin_amdgcn_exp2f((float)acc[0][0] * CRZ + gv0));
      float zz0 = __builtin_amdgcn_rcpf(
          1.f + __builtin_amdgcn_exp2f((float)acc[1][0] * CRZ + gv1));
      float hn2 = (float)acc[2][0] * CN + bn2;
      float tv0 = 2.f * __builtin_amdgcn_rcpf(
                            1.f + __builtin_amdgcn_exp2f(rr0 * hn2 + gv2)) -
                  1.f;
      float hnew = tv0 + zz0 * (ho - tv0);
      ho = hnew;
      int h8 = (int)rintf(hnew * SH);
      hb[1 - pb][q][col] = (char)h8;

      // light barrier: drain LDS only
      asm volatile("s_waitcnt lgkmcnt(0)" ::: "memory");
      __builtin_amdgcn_s_barrier();
      asm volatile("" ::: "memory");
    }

    // tail (last chunk): decoder partials of final state (in hb[1])
    if (c == 31 && w >= 12) {
      const int kb = w - 12;
      intx4_t b2 = *(const intx4_t*)&hb[1][nh >> 2][kb * 64 + q * 16];
      intx4_t f2 = {0, 0, 0, 0};
      f2 = __builtin_amdgcn_mfma_i32_16x16x64_i8(b2, wdfk, f2, 0, 0, 0);
      if (nh == 0) lp[kb][15 * 4 + q] = (float)f2[0];
    }
    __syncthreads();  // lp complete before BCE

    // ---- per-chunk BCE: slots 0..15 = logits t0c-1 .. t0c+14 (+tail) ----
    if (tid < 64) {
      const int slot = tid >> 2;
      const int gidx = t0c + slot - 1;
      if (gidx >= 0 && gidx <= 510) {
        float l =
            (lp[0][tid] + lp[1][tid] + lp[2][tid] + lp[3][tid]) * INV_S +
            bdec0;
        float gtv = gt[(size_t)(gidx + 1) * 256 + g * 4 + (tid & 3)];
        float t1 = log1pf(__expf(-fabsf(l)));
        loss +=
            gtv * (fmaxf(-l, 0.f) + t1) + (1.f - gtv) * (fmaxf(l, 0.f) + t1);
      }
    }
    // no extra sync needed: next chunk's first writes (xs) are disjoint from
    // lp/gt reads, and gi_s/wsb writes sit behind the slab barriers.
  }

  // loss lives only in wave 0 (tid<64)
  if (w == 0) {
    loss += __shfl_xor(loss, 1);
    loss += __shfl_xor(loss, 2);
    loss += __shfl_xor(loss, 4);
    loss += __shfl_xor(loss, 8);
    loss += __shfl_xor(loss, 16);
    loss += __shfl_xor(loss, 32);
    if (lane == 0) atomicAdd(out, loss);
  }
}

// ---------------- host ----------------
extern "C" void kernel_launch(void* const* d_in, const int* in_sizes, int n_in,
                              void* d_out, int out_size, void* d_ws,
                              size_t ws_size, hipStream_t stream) {
  const float* x = (const float*)d_in[0];     // [512,256,128]
  const float* gt = (const float*)d_in[1];    // [512,256,1]
  const float* Wih = (const float*)d_in[2];   // [768,128]
  const float* Whh = (const float*)d_in[3];   // [768,256]
  const float* bih = (const float*)d_in[4];   // [768]
  const float* bhh = (const float*)d_in[5];   // [768]
  const float* Wdec = (const float*)d_in[6];  // [1,256]
  const float* bdec = (const float*)d_in[7];  // [1]
  float* out = (float*)d_out;

  char* ws = (char*)d_ws;
  char* Wq = ws;                          // 196608 B
  char* wdq = ws + 196608;                // 256 B (pad 512)
  __bf16* Wihb = (__bf16*)(ws + 197120);  // 196608 B

  prep_kernel<<<256, 256, 0, stream>>>(Whh, Wdec, Wih, Wq, wdq, Wihb, out);
  rec2_kernel<<<64, 1024, 0, stream>>>(Wq, wdq, x, gt, bdec, bhh, bih, Wihb,
                                       out);
}